// Round 14
// baseline (541.612 us; speedup 1.0000x reference)
//
#include <hip/hip_runtime.h>

// GraphNet forward. Round 14: barrier-free grid-strided edge MFMA.
// r13 edge_mfma (112us) was barrier/latency-bound (MfmaUtil 4.6%, VALU 29%,
// ~2x its 55us stream floor). New: wave-owned 16-edge tiles; W B-frags in
// registers (loaded once, linear image); A-frags per-lane direct from
// global (attr cvt / xb rows); C-transpose via WAVE-LOCAL LDS (no
// __syncthreads anywhere). Gather accepted at ~3 TB/s L3-random wall
// (r12/r13 convergence). xconvert+precompute merged.

typedef unsigned int uint;
typedef unsigned short ushort;
typedef __attribute__((ext_vector_type(8))) short bf16x8;
typedef __attribute__((ext_vector_type(4))) float f32x4;

#define BW 128          // nodes per bucket (sort)
#define BSHIFT 7
#define NBMAX 784       // max buckets (N=100000 -> 782)
#define DC 8192         // edges per distribute block
#define EMASK 0x1FFFFFu // 21 bits of edge id

#define LDF4(p) (*reinterpret_cast<const float4*>(p))

__device__ __forceinline__ ushort f2bf(float f) {
  uint u = __float_as_uint(f);
  u += 0x7FFFu + ((u >> 16) & 1u);
  return (ushort)(u >> 16);
}

// swizzled ushort index of 16B chunk (row, kb) in [row][64] bf16 tile
__device__ __forceinline__ int aswz(int row, int kb) {
  return row * 64 + ((kb ^ (row & 7)) << 3);
}
// [row][128] tile (kb 0..15)
__device__ __forceinline__ int nswz(int row, int kb) {
  return row * 128 + (((kb & 8) | ((kb ^ row) & 7)) << 3);
}
// [row][192] tile (kb 0..23)
__device__ __forceinline__ int aswz192(int row, int kb) {
  return row * 192 + (((kb & 24) | ((kb ^ row) & 7)) << 3);
}

// ---- merged: x->bf16 convert (blocks 1..) + weight-image build (block 0)
__global__ __launch_bounds__(256) void init_kernel(
    const float* __restrict__ x, ushort* __restrict__ xb, int n16,
    const float* __restrict__ u, const float* __restrict__ W_eb,
    const float* __restrict__ b_eb, const float* __restrict__ W_nb,
    const float* __restrict__ b_nb, const float* __restrict__ W_d1,
    const float* __restrict__ W_d2, float* __restrict__ eb_init,
    float* __restrict__ nb_init, ushort* __restrict__ wt_lin,
    ushort* __restrict__ wnb_img, ushort* __restrict__ wtd1_img,
    ushort* __restrict__ w2_img) {
  if (blockIdx.x == 0) {
    int j = threadIdx.x;
    if (j >= 64) return;
    float ae = b_eb[j], an = b_nb[j];
    for (int k = 0; k < 64; ++k) {
      float uk = u[k];
      ae = fmaf(uk, W_eb[(48 + k) * 64 + j], ae);
      an = fmaf(uk, W_nb[(80 + k) * 64 + j], an);
    }
    eb_init[j] = ae;
    nb_init[j] = an;
    // edge W image, LINEAR row-major [n][k] (register B-frags, no swizzle)
    for (int k = 0; k < 64; ++k)
      wt_lin[j * 64 + k] = (k < 48) ? f2bf(W_eb[k * 64 + j]) : (ushort)0;
    for (int k = 0; k < 128; ++k) {
      ushort v = (k < 80) ? f2bf(W_nb[k * 64 + j]) : (ushort)0;
      wnb_img[nswz(j, k >> 3) + (k & 7)] = v;
    }
    for (int k = 0; k < 192; ++k)
      wtd1_img[aswz192(j, k >> 3) + (k & 7)] = f2bf(W_d1[k * 64 + j]);
    if (j < 16)
      for (int k = 0; k < 64; ++k)
        w2_img[aswz(j, k >> 3) + (k & 7)] = f2bf(W_d2[k * 16 + j]);
    return;
  }
  int i = (blockIdx.x - 1) * 256 + threadIdx.x;
  if (i * 4 >= n16) return;
  float4 a = LDF4(x + i * 4);
  ushort4 o = {f2bf(a.x), f2bf(a.y), f2bf(a.z), f2bf(a.w)};
  *reinterpret_cast<ushort4*>(xb + i * 4) = o;
}

// ---- bucket histogram for both directions
__global__ __launch_bounds__(256) void bcount_kernel(
    const int* __restrict__ receivers, const int* __restrict__ senders,
    uint* __restrict__ bcnt_r, uint* __restrict__ bcnt_s, int E, int NB) {
  __shared__ uint hr[NBMAX], hs[NBMAX];
  int t = threadIdx.x;
  for (int i = t; i < NB; i += 256) { hr[i] = 0; hs[i] = 0; }
  __syncthreads();
  int stride = gridDim.x * 256;
  for (int e = blockIdx.x * 256 + t; e < E; e += stride) {
    atomicAdd(&hr[receivers[e] >> BSHIFT], 1u);
    atomicAdd(&hs[senders[e] >> BSHIFT], 1u);
  }
  __syncthreads();
  for (int i = t; i < NB; i += 256) {
    if (hr[i]) atomicAdd(&bcnt_r[i], hr[i]);
    if (hs[i]) atomicAdd(&bcnt_s[i], hs[i]);
  }
}

// ---- exclusive scan of both bucket-count arrays (single block, 4/thread)
__global__ __launch_bounds__(256) void bscan_kernel(
    const uint* __restrict__ bcnt_r, const uint* __restrict__ bcnt_s,
    uint* __restrict__ start_r, uint* __restrict__ start_s,
    uint* __restrict__ cur_r, uint* __restrict__ cur_s, int E, int NB) {
  __shared__ uint ts[256];
  int t = threadIdx.x;
  #pragma unroll
  for (int pass = 0; pass < 2; ++pass) {
    const uint* cnt = pass ? bcnt_s : bcnt_r;
    uint* start = pass ? start_s : start_r;
    uint* cur = pass ? cur_s : cur_r;
    uint loc[4]; uint tsum = 0;
    #pragma unroll
    for (int q = 0; q < 4; ++q) {
      int i = t * 4 + q;
      loc[q] = (i < NB) ? cnt[i] : 0;
      tsum += loc[q];
    }
    ts[t] = tsum;
    __syncthreads();
    for (int off = 1; off < 256; off <<= 1) {
      uint a = (t >= off) ? ts[t - off] : 0;
      __syncthreads();
      ts[t] += a;
      __syncthreads();
    }
    uint run = ts[t] - tsum;
    #pragma unroll
    for (int q = 0; q < 4; ++q) {
      int i = t * 4 + q;
      if (i < NB) { start[i] = run; cur[i] = run; run += loc[q]; }
    }
    if (t == 0) start[NB] = (uint)E;
    __syncthreads();
  }
}

// ---- bucket-sort edge ids, both directions in one launch.
__global__ __launch_bounds__(256) void distribute_kernel(
    const int* __restrict__ receivers, const int* __restrict__ senders,
    uint* __restrict__ gcur_r, uint* __restrict__ gcur_s,
    uint* __restrict__ tmp_r, uint* __restrict__ tmp_s, int E, int NB) {
  __shared__ uint hist[NBMAX], lstart[NBMAX], cur[NBMAX], gbase[NBMAX];
  __shared__ uint ids[DC];
  __shared__ ushort idsB[DC];
  __shared__ uint ts[256];
  int dir = blockIdx.x & 1;
  const int* key = dir ? senders : receivers;
  uint* g_cursor = dir ? gcur_s : gcur_r;
  uint* tmp = dir ? tmp_s : tmp_r;
  int t = threadIdx.x;
  int base = (blockIdx.x >> 1) * DC;
  int cact = min(DC, E - base);
  for (int i = t; i < NB; i += 256) hist[i] = 0;
  __syncthreads();
  for (int k = 0; k < DC / 256; ++k) {
    int j = k * 256 + t;
    if (j < cact) atomicAdd(&hist[key[base + j] >> BSHIFT], 1u);
  }
  __syncthreads();
  {
    uint loc[4]; uint tsum = 0;
    #pragma unroll
    for (int q = 0; q < 4; ++q) {
      int i = t * 4 + q;
      loc[q] = (i < NB) ? hist[i] : 0;
      tsum += loc[q];
    }
    ts[t] = tsum;
    __syncthreads();
    for (int off = 1; off < 256; off <<= 1) {
      uint a = (t >= off) ? ts[t - off] : 0;
      __syncthreads();
      ts[t] += a;
      __syncthreads();
    }
    uint run = ts[t] - tsum;
    #pragma unroll
    for (int q = 0; q < 4; ++q) {
      int i = t * 4 + q;
      if (i < NB) { lstart[i] = run; cur[i] = run; run += loc[q]; }
    }
  }
  __syncthreads();
  for (int i = t; i < NB; i += 256)
    if (hist[i]) gbase[i] = atomicAdd(&g_cursor[i], hist[i]);
  for (int k = 0; k < DC / 256; ++k) {
    int j = k * 256 + t;
    if (j < cact) {
      int e = base + j;
      int kk = key[e];
      uint b = (uint)(kk >> BSHIFT);
      uint slot = atomicAdd(&cur[b], 1u);
      ids[slot] = ((uint)(kk & (BW - 1)) << 21) | (uint)e;
      idsB[slot] = (ushort)b;
    }
  }
  __syncthreads();
  for (int j = t; j < cact; j += 256) {
    uint b2 = idsB[j];
    tmp[gbase[b2] + ((uint)j - lstart[b2])] = ids[j];
  }
}

// ---- per-bucket counting sort to full per-node order.
__global__ __launch_bounds__(256) void bucketsort_kernel(
    const uint* __restrict__ tmp_r, const uint* __restrict__ tmp_s,
    const uint* __restrict__ start_r, const uint* __restrict__ start_s,
    uint* __restrict__ eidx_r, uint* __restrict__ eidx_s,
    uint* __restrict__ row_ptr_r, uint* __restrict__ row_ptr_s,
    uint* __restrict__ cnt_r, uint* __restrict__ cnt_s, int N) {
  __shared__ uint hist[BW], pfx[BW], cur[BW];
  int d = blockIdx.x & 1;
  int b = blockIdx.x >> 1;
  const uint* tmp = d ? tmp_s : tmp_r;
  const uint* start = d ? start_s : start_r;
  uint* eidx = d ? eidx_s : eidx_r;
  uint* row_ptr = d ? row_ptr_s : row_ptr_r;
  uint* cnt = d ? cnt_s : cnt_r;
  int t = threadIdx.x;
  if (t < BW) hist[t] = 0;
  __syncthreads();
  int beg = (int)start[b], end = (int)start[b + 1];
  for (int i = beg + t; i < end; i += 256) atomicAdd(&hist[tmp[i] >> 21], 1u);
  __syncthreads();
  if (t < BW) pfx[t] = hist[t];
  __syncthreads();
  for (int off = 1; off < BW; off <<= 1) {
    uint a = 0;
    if (t < BW && t >= off) a = pfx[t - off];
    __syncthreads();
    if (t < BW) pfx[t] += a;
    __syncthreads();
  }
  if (t < BW) cur[t] = pfx[t] - hist[t];
  __syncthreads();
  for (int i = beg + t; i < end; i += 256) {
    uint v = tmp[i];
    uint nl = v >> 21;
    uint p = atomicAdd(&cur[nl], 1u);
    eidx[beg + p] = v & EMASK;
  }
  int nbase = b * BW;
  if (t < BW && nbase + t < N) {
    cnt[nbase + t] = hist[t];
    row_ptr[nbase + t] = (uint)beg + pfx[t] - hist[t];
  }
}

// ---- edge MLP via MFMA, barrier-free, grid-strided waves.
// Wave owns 16-edge tiles. B-frags (W) in registers, loaded once.
// A-frags per-lane direct from global. C via wave-local LDS bounce.
__global__ __launch_bounds__(256, 4) void edge_mfma_kernel(
    const float* __restrict__ edge_attr, const ushort* __restrict__ xb,
    const int* __restrict__ senders, const int* __restrict__ receivers,
    const ushort* __restrict__ wt_lin, const float* __restrict__ eb_init,
    ushort* __restrict__ e_h, int E, int ntiles) {
  __shared__ ushort Clds[4][16 * 72];  // per-wave slices, wave-local use
  int t = threadIdx.x;
  int wid = t >> 6, l = t & 63;
  int lrow = l & 15, lk = l >> 4;
  // B-fragments: W[n = nt*16+lrow][k = lk*8.. / 32+lk*8..], held in regs
  bf16x8 b0[4], b1[4];
  float ebi[4];
  #pragma unroll
  for (int nt = 0; nt < 4; ++nt) {
    const ushort* wr = wt_lin + (nt * 16 + lrow) * 64;
    b0[nt] = *reinterpret_cast<const bf16x8*>(wr + lk * 8);
    b1[nt] = *reinterpret_cast<const bf16x8*>(wr + 32 + lk * 8);
    ebi[nt] = eb_init[nt * 16 + lrow];
  }
  const bf16x8 zero8 = {0, 0, 0, 0, 0, 0, 0, 0};
  int gw = blockIdx.x * 4 + wid;
  int nw = gridDim.x * 4;
  for (int tile = gw; tile < ntiles; tile += nw) {
    int e = tile * 16 + lrow;
    int ec = min(e, E - 1);  // clamped for safe OOB loads (rows not stored)
    bf16x8 a0, a1;
    if (lk < 2) {
      const float* ap = edge_attr + (size_t)ec * 16 + lk * 8;
      float4 f0 = LDF4(ap), f1 = LDF4(ap + 4);
      union { ushort h[8]; bf16x8 v; } pk;
      pk.h[0] = f2bf(f0.x); pk.h[1] = f2bf(f0.y);
      pk.h[2] = f2bf(f0.z); pk.h[3] = f2bf(f0.w);
      pk.h[4] = f2bf(f1.x); pk.h[5] = f2bf(f1.y);
      pk.h[6] = f2bf(f1.z); pk.h[7] = f2bf(f1.w);
      a0 = pk.v;
      int s = senders[ec];
      a1 = *reinterpret_cast<const bf16x8*>(xb + (size_t)s * 16 + lk * 8);
    } else {
      int r = receivers[ec];
      a0 = *reinterpret_cast<const bf16x8*>(xb + (size_t)r * 16 +
                                            (lk - 2) * 8);
      a1 = zero8;
    }
    f32x4 acc[4];
    #pragma unroll
    for (int nt = 0; nt < 4; ++nt) {
      acc[nt] = f32x4{ebi[nt], ebi[nt], ebi[nt], ebi[nt]};
      acc[nt] =
          __builtin_amdgcn_mfma_f32_16x16x32_bf16(a0, b0[nt], acc[nt], 0, 0, 0);
      acc[nt] =
          __builtin_amdgcn_mfma_f32_16x16x32_bf16(a1, b1[nt], acc[nt], 0, 0, 0);
    }
    // wave-local transpose bounce (no barrier: single-wave producer/consumer)
    int m0 = (l >> 4) * 4;
    #pragma unroll
    for (int nt = 0; nt < 4; ++nt) {
      #pragma unroll
      for (int reg = 0; reg < 4; ++reg) {
        Clds[wid][(m0 + reg) * 72 + nt * 16 + lrow] =
            f2bf(fmaxf(acc[nt][reg], 0.f));
      }
    }
    int sm = l >> 2, ch = l & 3;
    int ge = tile * 16 + sm;
    uint4 c0 = *reinterpret_cast<const uint4*>(&Clds[wid][sm * 72 + ch * 16]);
    uint4 c1 =
        *reinterpret_cast<const uint4*>(&Clds[wid][sm * 72 + ch * 16 + 8]);
    if (ge < E) {
      uint4* dst = reinterpret_cast<uint4*>(e_h + (size_t)ge * 64 + ch * 16);
      dst[0] = c0;
      dst[1] = c1;
    }
  }
}

// ---- gather, both directions in one launch; wave per node; contiguous
// half-wave ranges + index prefetch (r13, near L3-random wall).
__global__ __launch_bounds__(256, 2) void gather_kernel(
    const ushort* __restrict__ e_h, const uint* __restrict__ row_ptr_r,
    const uint* __restrict__ cnt_r, const uint* __restrict__ eidx_r,
    const uint* __restrict__ row_ptr_s, const uint* __restrict__ cnt_s,
    const uint* __restrict__ eidx_s, float* __restrict__ sum_recv,
    float* __restrict__ sum_sent, int N) {
  int dir = blockIdx.x & 1;
  const uint* row_ptr = dir ? row_ptr_s : row_ptr_r;
  const uint* cnt = dir ? cnt_s : cnt_r;
  const uint* eidx = dir ? eidx_s : eidx_r;
  float* out = dir ? sum_sent : sum_recv;
  int n = (blockIdx.x >> 1) * 4 + (threadIdx.x >> 6);
  if (n >= N) return;
  const uint* eh32 = reinterpret_cast<const uint*>(e_h);
  int lane = threadIdx.x & 63;
  int half = lane >> 5;
  int l = lane & 31;
  int beg = (int)row_ptr[n];
  int c = (int)cnt[n];
  int c0 = (c + 1) >> 1;
  int b0 = beg + (half ? c0 : 0);
  int cN = half ? (c - c0) : c0;
  float a0 = 0, a1 = 0, b0f = 0, b1f = 0, c0f = 0, c1f = 0, d0f = 0, d1f = 0;
  int i = 0;
  uint e0 = 0, e1 = 0, e2 = 0, e3 = 0;
  if (cN >= 4) {
    e0 = eidx[b0]; e1 = eidx[b0 + 1]; e2 = eidx[b0 + 2]; e3 = eidx[b0 + 3];
  }
  for (; i + 8 <= cN; i += 4) {
    uint w0 = eh32[(size_t)e0 * 32 + l];
    uint w1 = eh32[(size_t)e1 * 32 + l];
    uint w2 = eh32[(size_t)e2 * 32 + l];
    uint w3 = eh32[(size_t)e3 * 32 + l];
    e0 = eidx[b0 + i + 4]; e1 = eidx[b0 + i + 5];
    e2 = eidx[b0 + i + 6]; e3 = eidx[b0 + i + 7];
    a0 += __uint_as_float(w0 << 16);
    a1 += __uint_as_float(w0 & 0xFFFF0000u);
    b0f += __uint_as_float(w1 << 16);
    b1f += __uint_as_float(w1 & 0xFFFF0000u);
    c0f += __uint_as_float(w2 << 16);
    c1f += __uint_as_float(w2 & 0xFFFF0000u);
    d0f += __uint_as_float(w3 << 16);
    d1f += __uint_as_float(w3 & 0xFFFF0000u);
  }
  if (i + 4 <= cN) {
    uint w0 = eh32[(size_t)e0 * 32 + l];
    uint w1 = eh32[(size_t)e1 * 32 + l];
    uint w2 = eh32[(size_t)e2 * 32 + l];
    uint w3 = eh32[(size_t)e3 * 32 + l];
    a0 += __uint_as_float(w0 << 16);
    a1 += __uint_as_float(w0 & 0xFFFF0000u);
    b0f += __uint_as_float(w1 << 16);
    b1f += __uint_as_float(w1 & 0xFFFF0000u);
    c0f += __uint_as_float(w2 << 16);
    c1f += __uint_as_float(w2 & 0xFFFF0000u);
    d0f += __uint_as_float(w3 << 16);
    d1f += __uint_as_float(w3 & 0xFFFF0000u);
    i += 4;
  }
  for (; i < cN; ++i) {
    uint w0 = eh32[(size_t)eidx[b0 + i] * 32 + l];
    a0 += __uint_as_float(w0 << 16);
    a1 += __uint_as_float(w0 & 0xFFFF0000u);
  }
  a0 = (a0 + b0f) + (c0f + d0f);
  a1 = (a1 + b1f) + (c1f + d1f);
  a0 += __shfl_xor(a0, 32);
  a1 += __shfl_xor(a1, 32);
  if (half == 0) {
    float2 t = {a0, a1};
    *reinterpret_cast<float2*>(out + (size_t)n * 64 + 2 * l) = t;
  }
}

// ---- node block via MFMA: n_h(bf16) = relu([sum_recv, x]@W_nb + nb_init)
__global__ __launch_bounds__(256, 2) void node_mfma_kernel(
    const float* __restrict__ sum_recv, const ushort* __restrict__ xb,
    const ushort* __restrict__ wnb_img, const float* __restrict__ nb_init,
    ushort* __restrict__ n_h, int N) {
  __shared__ ushort Alds[64 * 128];      // 16 KB
  __shared__ ushort Wlds[64 * 128];      // 16 KB
  __shared__ ushort Clds[4][16 * 72];    // 9 KB
  int t = threadIdx.x;
  int base = blockIdx.x * 64;
  {
    const uint4* src = reinterpret_cast<const uint4*>(wnb_img);
    uint4* dst = reinterpret_cast<uint4*>(Wlds);
    #pragma unroll
    for (int i = 0; i < 4; ++i) dst[t + 256 * i] = src[t + 256 * i];
  }
  {
    int m = t >> 2, part = t & 3;
    int n = base + m;
    bool val = n < N;
    if (part < 2) {
      #pragma unroll
      for (int q = 0; q < 4; ++q) {
        int c = part * 4 + q;
        union { ushort h[8]; uint4 qq; } pk;
        if (val) {
          const float* src = sum_recv + (size_t)n * 64 + c * 8;
          float4 f0 = LDF4(src), f1 = LDF4(src + 4);
          pk.h[0] = f2bf(f0.x); pk.h[1] = f2bf(f0.y);
          pk.h[2] = f2bf(f0.z); pk.h[3] = f2bf(f0.w);
          pk.h[4] = f2bf(f1.x); pk.h[5] = f2bf(f1.y);
          pk.h[6] = f2bf(f1.z); pk.h[7] = f2bf(f1.w);
        } else {
          pk.qq = uint4{0, 0, 0, 0};
        }
        *reinterpret_cast<uint4*>(&Alds[nswz(m, c)]) = pk.qq;
      }
    } else if (part == 2) {
      uint4 w0 = {0, 0, 0, 0}, w1 = {0, 0, 0, 0};
      if (val) {
        const uint4* xp = reinterpret_cast<const uint4*>(xb + (size_t)n * 16);
        w0 = xp[0]; w1 = xp[1];
      }
      *reinterpret_cast<uint4*>(&Alds[nswz(m, 8)]) = w0;
      *reinterpret_cast<uint4*>(&Alds[nswz(m, 9)]) = w1;
      *reinterpret_cast<uint4*>(&Alds[nswz(m, 10)]) = uint4{0, 0, 0, 0};
      *reinterpret_cast<uint4*>(&Alds[nswz(m, 11)]) = uint4{0, 0, 0, 0};
    } else {
      #pragma unroll
      for (int q = 0; q < 4; ++q)
        *reinterpret_cast<uint4*>(&Alds[nswz(m, 12 + q)]) = uint4{0, 0, 0, 0};
    }
  }
  __syncthreads();
  int wid = t >> 6, l = t & 63;
  int lrow = l & 15, lk = l >> 4;
  int arow = wid * 16 + lrow;
  bf16x8 afr[4];
  #pragma unroll
  for (int g = 0; g < 4; ++g)
    afr[g] = *reinterpret_cast<const bf16x8*>(&Alds[nswz(arow, g * 4 + lk)]);
  f32x4 acc[4];
  #pragma unroll
  for (int nt = 0; nt < 4; ++nt) {
    float nbi = nb_init[nt * 16 + lrow];
    acc[nt] = f32x4{nbi, nbi, nbi, nbi};
    #pragma unroll
    for (int g = 0; g < 4; ++g) {
      bf16x8 b = *reinterpret_cast<const bf16x8*>(
          &Wlds[nswz(nt * 16 + lrow, g * 4 + lk)]);
      acc[nt] =
          __builtin_amdgcn_mfma_f32_16x16x32_bf16(afr[g], b, acc[nt], 0, 0, 0);
    }
  }
  int m0 = (l >> 4) * 4;
  #pragma unroll
  for (int nt = 0; nt < 4; ++nt) {
    #pragma unroll
    for (int reg = 0; reg < 4; ++reg) {
      Clds[wid][(m0 + reg) * 72 + nt * 16 + lrow] =
          f2bf(fmaxf(acc[nt][reg], 0.f));
    }
  }
  __syncthreads();
  int sm = l >> 2, ch = l & 3;
  int gn = base + wid * 16 + sm;
  uint4 c0 = *reinterpret_cast<const uint4*>(&Clds[wid][sm * 72 + ch * 16]);
  uint4 c1 = *reinterpret_cast<const uint4*>(&Clds[wid][sm * 72 + ch * 16 + 8]);
  if (gn < N) {
    uint4* dst = reinterpret_cast<uint4*>(n_h + (size_t)gn * 64 + ch * 16);
    dst[0] = c0;
    dst[1] = c1;
  }
}

// ---- column sums of sum_recv (fp32) and n_h (bf16)
__global__ __launch_bounds__(256) void reduce_kernel(
    const float* __restrict__ sum_recv, const ushort* __restrict__ n_h,
    float* __restrict__ e_sum, float* __restrict__ n_sum, int N) {
  __shared__ float ls[128];
  if (threadIdx.x < 128) ls[threadIdx.x] = 0.f;
  __syncthreads();
  int g = threadIdx.x & 15;
  int tid = blockIdx.x * blockDim.x + threadIdx.x;
  int row0 = tid >> 4;
  int rstride = (gridDim.x * blockDim.x) >> 4;
  float pe[4] = {0, 0, 0, 0}, pn[4] = {0, 0, 0, 0};
  for (int r = row0; r < N; r += rstride) {
    float4 a = LDF4(sum_recv + (size_t)r * 64 + g * 4);
    uint2 b = *reinterpret_cast<const uint2*>(n_h + (size_t)r * 64 + g * 4);
    pe[0] += a.x; pe[1] += a.y; pe[2] += a.z; pe[3] += a.w;
    pn[0] += __uint_as_float(b.x << 16);
    pn[1] += __uint_as_float(b.x & 0xFFFF0000u);
    pn[2] += __uint_as_float(b.y << 16);
    pn[3] += __uint_as_float(b.y & 0xFFFF0000u);
  }
  #pragma unroll
  for (int i = 0; i < 4; ++i) {
    atomicAdd(&ls[g * 4 + i], pe[i]);
    atomicAdd(&ls[64 + g * 4 + i], pn[i]);
  }
  __syncthreads();
  if (threadIdx.x < 64) {
    atomicAdd(&e_sum[threadIdx.x], ls[threadIdx.x]);
    atomicAdd(&n_sum[threadIdx.x], ls[64 + threadIdx.x]);
  }
}

// ---- global block + fold u2 into d1_init
__global__ void global_kernel(const float* __restrict__ u,
                              const float* __restrict__ e_sum,
                              const float* __restrict__ n_sum,
                              const float* __restrict__ W_gb,
                              const float* __restrict__ b_gb,
                              const float* __restrict__ W_d1,
                              const float* __restrict__ b_d1,
                              float* __restrict__ d1_init, float Ef, float Nf) {
  __shared__ float gin[192];
  __shared__ float u2s[64];
  int j = threadIdx.x;  // 64 threads
  gin[j] = e_sum[j] / Ef;
  gin[64 + j] = n_sum[j] / Nf;
  gin[128 + j] = u[j];
  __syncthreads();
  float a = b_gb[j];
  for (int k = 0; k < 192; ++k) a = fmaf(gin[k], W_gb[k * 64 + j], a);
  u2s[j] = fmaxf(a, 0.f);
  __syncthreads();
  float d = b_d1[j];
  for (int k = 0; k < 64; ++k) d = fmaf(u2s[k], W_d1[(192 + k) * 64 + j], d);
  d1_init[j] = d;
}

// ---- decoder via MFMA: out = relu(A@W_d1 + d1_init) @ W_d2 + b_d2
__global__ __launch_bounds__(256, 2) void decoder_mfma_kernel(
    const float* __restrict__ sum_recv, const float* __restrict__ sum_sent,
    const uint* __restrict__ cnt_r, const uint* __restrict__ cnt_s,
    const ushort* __restrict__ n_h, const ushort* __restrict__ wtd1_img,
    const float* __restrict__ d1_init, const ushort* __restrict__ w2_img,
    const float* __restrict__ b_d2, float* __restrict__ out, int N) {
  __shared__ ushort Alds[64 * 192];   // 24 KB
  __shared__ ushort Wlds[64 * 192];   // 24 KB
  __shared__ ushort Hlds[64 * 64];    // 8 KB
  __shared__ ushort W2lds[16 * 64];   // 2 KB
  int t = threadIdx.x;
  int base = blockIdx.x * 64;
  {
    const uint4* src = reinterpret_cast<const uint4*>(wtd1_img);
    uint4* dst = reinterpret_cast<uint4*>(Wlds);
    #pragma unroll
    for (int i = 0; i < 6; ++i) dst[t + 256 * i] = src[t + 256 * i];
    if (t < 128)
      reinterpret_cast<uint4*>(W2lds)[t] =
          reinterpret_cast<const uint4*>(w2_img)[t];
  }
  {
    int m = t >> 2;
    int n = base + m;
    bool val = n < N;
    float invr = 0.f, invs = 0.f;
    if (val) {
      invr = 1.f / fmaxf((float)cnt_r[n], 1.f);
      invs = 1.f / fmaxf((float)cnt_s[n], 1.f);
    }
    int c0 = (t & 3) * 6;
    for (int c = c0; c < c0 + 6; ++c) {
      union { ushort h[8]; uint4 q; } pk;
      if (val) {
        if (c >= 16) {
          pk.q = *reinterpret_cast<const uint4*>(n_h + (size_t)n * 64 +
                                                 (c - 16) * 8);
        } else {
          const float* src;
          float scl;
          if (c < 8) { src = sum_recv + (size_t)n * 64 + c * 8; scl = invr; }
          else       { src = sum_sent + (size_t)n * 64 + (c - 8) * 8; scl = invs; }
          float4 f0 = LDF4(src), f1 = LDF4(src + 4);
          pk.h[0] = f2bf(f0.x * scl); pk.h[1] = f2bf(f0.y * scl);
          pk.h[2] = f2bf(f0.z * scl); pk.h[3] = f2bf(f0.w * scl);
          pk.h[4] = f2bf(f1.x * scl); pk.h[5] = f2bf(f1.y * scl);
          pk.h[6] = f2bf(f1.z * scl); pk.h[7] = f2bf(f1.w * scl);
        }
      } else {
        pk.q = uint4{0, 0, 0, 0};
      }
      *reinterpret_cast<uint4*>(&Alds[aswz192(m, c)]) = pk.q;
    }
  }
  __syncthreads();
  int wid = t >> 6, l = t & 63;
  int lrow = l & 15, lk = l >> 4;
  int arow = wid * 16 + lrow;
  bf16x8 afr[6];
  #pragma unroll
  for (int g = 0; g < 6; ++g)
    afr[g] = *reinterpret_cast<const bf16x8*>(&Alds[aswz192(arow, g * 4 + lk)]);
  f32x4 acc[4];
  #pragma unroll
  for (int nt = 0; nt < 4; ++nt) {
    float di = d1_init[nt * 16 + lrow];
    acc[nt] = f32x4{di, di, di, di};
    #pragma unroll
    for (int g = 0; g < 6; ++g) {
      bf16x8 b = *reinterpret_cast<const bf16x8*>(
          &Wlds[aswz192(nt * 16 + lrow, g * 4 + lk)]);
      acc[nt] =
          __builtin_amdgcn_mfma_f32_16x16x32_bf16(afr[g], b, acc[nt], 0, 0, 0);
    }
  }
  int m0 = (l >> 4) * 4;
  #pragma unroll
  for (int nt = 0; nt < 4; ++nt) {
    #pragma unroll
    for (int reg = 0; reg < 4; ++reg) {
      int hm = wid * 16 + m0 + reg;
      int hn = nt * 16 + lrow;
      Hlds[hm * 64 + (((hn >> 3) ^ (hm & 7)) << 3) + (hn & 7)] =
          f2bf(fmaxf(acc[nt][reg], 0.f));
    }
  }
  __syncthreads();
  bf16x8 a20 = *reinterpret_cast<const bf16x8*>(&Hlds[aswz(arow, lk)]);
  bf16x8 a21 = *reinterpret_cast<const bf16x8*>(&Hlds[aswz(arow, 4 + lk)]);
  bf16x8 b20 = *reinterpret_cast<const bf16x8*>(&W2lds[aswz(lrow, lk)]);
  bf16x8 b21 = *reinterpret_cast<const bf16x8*>(&W2lds[aswz(lrow, 4 + lk)]);
  float bi = b_d2[lrow];
  f32x4 o = f32x4{bi, bi, bi, bi};
  o = __builtin_amdgcn_mfma_f32_16x16x32_bf16(a20, b20, o, 0, 0, 0);
  o = __builtin_amdgcn_mfma_f32_16x16x32_bf16(a21, b21, o, 0, 0, 0);
  #pragma unroll
  for (int reg = 0; reg < 4; ++reg) {
    int ge = base + wid * 16 + m0 + reg;
    if (ge < N) out[(size_t)ge * 16 + lrow] = o[reg];
  }
}

extern "C" void kernel_launch(void* const* d_in, const int* in_sizes, int n_in,
                              void* d_out, int out_size, void* d_ws,
                              size_t ws_size, hipStream_t stream) {
  const float* x         = (const float*)d_in[0];
  const float* edge_attr = (const float*)d_in[1];
  const float* u         = (const float*)d_in[2];
  const int*   senders   = (const int*)d_in[3];
  const int*   receivers = (const int*)d_in[4];
  const float* W_eb = (const float*)d_in[7];
  const float* b_eb = (const float*)d_in[8];
  const float* W_nb = (const float*)d_in[9];
  const float* b_nb = (const float*)d_in[10];
  const float* W_gb = (const float*)d_in[11];
  const float* b_gb = (const float*)d_in[12];
  const float* W_d1 = (const float*)d_in[13];
  const float* b_d1 = (const float*)d_in[14];
  const float* W_d2 = (const float*)d_in[15];
  const float* b_d2 = (const float*)d_in[16];

  int N = in_sizes[0] / 16;
  int E = in_sizes[1] / 16;
  int NB = (N + BW - 1) >> BSHIFT;  // 782 for N=100000
  int NDB = (E + DC - 1) / DC;      // distribute chunks per direction
  int ntiles = (E + 15) / 16;

  char* w = (char*)d_ws;
  ushort* e_h = (ushort*)w;          w += (size_t)E * 64 * 2;
  float* sum_recv = (float*)w;       w += (size_t)N * 64 * 4;
  float* sum_sent = (float*)w;       w += (size_t)N * 64 * 4;
  ushort* n_h = (ushort*)w;          w += (size_t)N * 64 * 2;
  uint* tmp_r = (uint*)w;            w += (size_t)E * 4;
  uint* tmp_s = (uint*)w;            w += (size_t)E * 4;
  uint* eidx_r = (uint*)w;           w += (size_t)E * 4;
  uint* eidx_s = (uint*)w;           w += (size_t)E * 4;
  uint* row_ptr_r = (uint*)w;        w += (size_t)N * 4;
  uint* row_ptr_s = (uint*)w;        w += (size_t)N * 4;
  uint* cnt_r = (uint*)w;            w += (size_t)N * 4;
  uint* cnt_s = (uint*)w;            w += (size_t)N * 4;
  ushort* xb = (ushort*)w;           w += (size_t)N * 16 * 2;
  ushort* wt_lin = (ushort*)w;       w += (size_t)64 * 64 * 2;
  ushort* wnb_img = (ushort*)w;      w += (size_t)64 * 128 * 2;
  ushort* wtd1_img = (ushort*)w;     w += (size_t)64 * 192 * 2;
  ushort* w2_img = (ushort*)w;       w += (size_t)16 * 64 * 2;
  uint* start_r = (uint*)w;          w += (size_t)(NB + 1) * 4;
  uint* start_s = (uint*)w;          w += (size_t)(NB + 1) * 4;
  uint* cur_r = (uint*)w;            w += (size_t)NB * 4;
  uint* cur_s = (uint*)w;            w += (size_t)NB * 4;
  // zeroed region
  uint* bcnt_r = (uint*)w;           w += (size_t)NBMAX * 4;
  uint* bcnt_s = (uint*)w;           w += (size_t)NBMAX * 4;
  float* e_sum = (float*)w;          w += 64 * 4;
  float* n_sum = (float*)w;          w += 64 * 4;
  // small non-zeroed
  float* eb_init = (float*)w;        w += 64 * 4;
  float* nb_init = (float*)w;        w += 64 * 4;
  float* d1_init = (float*)w;        w += 64 * 4;

  size_t zero_bytes = (size_t)(2 * NBMAX + 128) * 4;
  hipMemsetAsync(bcnt_r, 0, zero_bytes, stream);

  hipLaunchKernelGGL(init_kernel, dim3(1 + (N * 16 / 4 + 255) / 256), dim3(256),
                     0, stream, x, xb, N * 16, u, W_eb, b_eb, W_nb, b_nb, W_d1,
                     W_d2, eb_init, nb_init, wt_lin, wnb_img, wtd1_img, w2_img);
  hipLaunchKernelGGL(bcount_kernel, dim3(64), dim3(256), 0, stream, receivers,
                     senders, bcnt_r, bcnt_s, E, NB);
  hipLaunchKernelGGL(bscan_kernel, dim3(1), dim3(256), 0, stream, bcnt_r,
                     bcnt_s, start_r, start_s, cur_r, cur_s, E, NB);
  hipLaunchKernelGGL(distribute_kernel, dim3(2 * NDB), dim3(256), 0, stream,
                     receivers, senders, cur_r, cur_s, tmp_r, tmp_s, E, NB);
  hipLaunchKernelGGL(bucketsort_kernel, dim3(2 * NB), dim3(256), 0, stream,
                     tmp_r, tmp_s, start_r, start_s, eidx_r, eidx_s, row_ptr_r,
                     row_ptr_s, cnt_r, cnt_s, N);
  // edge MFMA kernel right before gathers: e_h stays L3-resident
  hipLaunchKernelGGL(edge_mfma_kernel, dim3(2048), dim3(256), 0, stream,
                     edge_attr, xb, senders, receivers, wt_lin, eb_init, e_h,
                     E, ntiles);
  hipLaunchKernelGGL(gather_kernel, dim3(2 * ((N + 3) / 4)), dim3(256), 0,
                     stream, e_h, row_ptr_r, cnt_r, eidx_r, row_ptr_s, cnt_s,
                     eidx_s, sum_recv, sum_sent, N);
  hipLaunchKernelGGL(node_mfma_kernel, dim3((N + 63) / 64), dim3(256), 0,
                     stream, sum_recv, xb, wnb_img, nb_init, n_h, N);
  hipLaunchKernelGGL(reduce_kernel, dim3(256), dim3(256), 0, stream, sum_recv,
                     n_h, e_sum, n_sum, N);
  hipLaunchKernelGGL(global_kernel, dim3(1), dim3(64), 0, stream, u, e_sum,
                     n_sum, W_gb, b_gb, W_d1, b_d1, d1_init, (float)E,
                     (float)N);
  hipLaunchKernelGGL(decoder_mfma_kernel, dim3((N + 63) / 64), dim3(256), 0,
                     stream, sum_recv, sum_sent, cnt_r, cnt_s, n_h, wtd1_img,
                     d1_init, w2_img, b_d2, (float*)d_out, N);
}

// Round 15
// 481.992 us; speedup vs baseline: 1.1237x; 1.1237x over previous
//
#include <hip/hip_runtime.h>

// GraphNet forward. Round 15: DELETE the random access instead of tuning it.
// r12-r14: gather pinned at ~3 TB/s on 410MB of random e_h rows. New
// escatter_kernel fuses edge-MLP + aggregation: processes edges in
// node-sorted (eidx) order, computes the MLP tile (r14's validated
// register-B-frag MFMA path), and segment-sums node runs straight into
// sum_recv/sum_sent via coalesced 256B fp32 atomic row-adds (~250K rows,
// ~100MB write-through). e_h never exists; both directions in one launch
// (MLP recompute is free at 5% MfmaUtil).

typedef unsigned int uint;
typedef unsigned short ushort;
typedef __attribute__((ext_vector_type(8))) short bf16x8;
typedef __attribute__((ext_vector_type(4))) float f32x4;

#define BW 128          // nodes per bucket (sort)
#define BSHIFT 7
#define NBMAX 784       // max buckets (N=100000 -> 782)
#define DC 8192         // edges per distribute block
#define EMASK 0x1FFFFFu // 21 bits of edge id

#define LDF4(p) (*reinterpret_cast<const float4*>(p))

__device__ __forceinline__ ushort f2bf(float f) {
  uint u = __float_as_uint(f);
  u += 0x7FFFu + ((u >> 16) & 1u);
  return (ushort)(u >> 16);
}

// swizzled ushort index of 16B chunk (row, kb) in [row][64] bf16 tile
__device__ __forceinline__ int aswz(int row, int kb) {
  return row * 64 + ((kb ^ (row & 7)) << 3);
}
// [row][128] tile (kb 0..15)
__device__ __forceinline__ int nswz(int row, int kb) {
  return row * 128 + (((kb & 8) | ((kb ^ row) & 7)) << 3);
}
// [row][192] tile (kb 0..23)
__device__ __forceinline__ int aswz192(int row, int kb) {
  return row * 192 + (((kb & 24) | ((kb ^ row) & 7)) << 3);
}

// ---- merged: x->bf16 convert (blocks 1..) + weight-image build (block 0)
__global__ __launch_bounds__(256) void init_kernel(
    const float* __restrict__ x, ushort* __restrict__ xb, int n16,
    const float* __restrict__ u, const float* __restrict__ W_eb,
    const float* __restrict__ b_eb, const float* __restrict__ W_nb,
    const float* __restrict__ b_nb, const float* __restrict__ W_d1,
    const float* __restrict__ W_d2, float* __restrict__ eb_init,
    float* __restrict__ nb_init, ushort* __restrict__ wt_lin,
    ushort* __restrict__ wnb_img, ushort* __restrict__ wtd1_img,
    ushort* __restrict__ w2_img) {
  if (blockIdx.x == 0) {
    int j = threadIdx.x;
    if (j >= 64) return;
    float ae = b_eb[j], an = b_nb[j];
    for (int k = 0; k < 64; ++k) {
      float uk = u[k];
      ae = fmaf(uk, W_eb[(48 + k) * 64 + j], ae);
      an = fmaf(uk, W_nb[(80 + k) * 64 + j], an);
    }
    eb_init[j] = ae;
    nb_init[j] = an;
    // edge W image, LINEAR row-major [n][k] (register B-frags)
    for (int k = 0; k < 64; ++k)
      wt_lin[j * 64 + k] = (k < 48) ? f2bf(W_eb[k * 64 + j]) : (ushort)0;
    for (int k = 0; k < 128; ++k) {
      ushort v = (k < 80) ? f2bf(W_nb[k * 64 + j]) : (ushort)0;
      wnb_img[nswz(j, k >> 3) + (k & 7)] = v;
    }
    for (int k = 0; k < 192; ++k)
      wtd1_img[aswz192(j, k >> 3) + (k & 7)] = f2bf(W_d1[k * 64 + j]);
    if (j < 16)
      for (int k = 0; k < 64; ++k)
        w2_img[aswz(j, k >> 3) + (k & 7)] = f2bf(W_d2[k * 16 + j]);
    return;
  }
  int i = (blockIdx.x - 1) * 256 + threadIdx.x;
  if (i * 4 >= n16) return;
  float4 a = LDF4(x + i * 4);
  ushort4 o = {f2bf(a.x), f2bf(a.y), f2bf(a.z), f2bf(a.w)};
  *reinterpret_cast<ushort4*>(xb + i * 4) = o;
}

// ---- bucket histogram for both directions
__global__ __launch_bounds__(256) void bcount_kernel(
    const int* __restrict__ receivers, const int* __restrict__ senders,
    uint* __restrict__ bcnt_r, uint* __restrict__ bcnt_s, int E, int NB) {
  __shared__ uint hr[NBMAX], hs[NBMAX];
  int t = threadIdx.x;
  for (int i = t; i < NB; i += 256) { hr[i] = 0; hs[i] = 0; }
  __syncthreads();
  int stride = gridDim.x * 256;
  for (int e = blockIdx.x * 256 + t; e < E; e += stride) {
    atomicAdd(&hr[receivers[e] >> BSHIFT], 1u);
    atomicAdd(&hs[senders[e] >> BSHIFT], 1u);
  }
  __syncthreads();
  for (int i = t; i < NB; i += 256) {
    if (hr[i]) atomicAdd(&bcnt_r[i], hr[i]);
    if (hs[i]) atomicAdd(&bcnt_s[i], hs[i]);
  }
}

// ---- exclusive scan of both bucket-count arrays (single block, 4/thread)
__global__ __launch_bounds__(256) void bscan_kernel(
    const uint* __restrict__ bcnt_r, const uint* __restrict__ bcnt_s,
    uint* __restrict__ start_r, uint* __restrict__ start_s,
    uint* __restrict__ cur_r, uint* __restrict__ cur_s, int E, int NB) {
  __shared__ uint ts[256];
  int t = threadIdx.x;
  #pragma unroll
  for (int pass = 0; pass < 2; ++pass) {
    const uint* cnt = pass ? bcnt_s : bcnt_r;
    uint* start = pass ? start_s : start_r;
    uint* cur = pass ? cur_s : cur_r;
    uint loc[4]; uint tsum = 0;
    #pragma unroll
    for (int q = 0; q < 4; ++q) {
      int i = t * 4 + q;
      loc[q] = (i < NB) ? cnt[i] : 0;
      tsum += loc[q];
    }
    ts[t] = tsum;
    __syncthreads();
    for (int off = 1; off < 256; off <<= 1) {
      uint a = (t >= off) ? ts[t - off] : 0;
      __syncthreads();
      ts[t] += a;
      __syncthreads();
    }
    uint run = ts[t] - tsum;
    #pragma unroll
    for (int q = 0; q < 4; ++q) {
      int i = t * 4 + q;
      if (i < NB) { start[i] = run; cur[i] = run; run += loc[q]; }
    }
    if (t == 0) start[NB] = (uint)E;
    __syncthreads();
  }
}

// ---- bucket-sort edge ids, both directions in one launch.
__global__ __launch_bounds__(256) void distribute_kernel(
    const int* __restrict__ receivers, const int* __restrict__ senders,
    uint* __restrict__ gcur_r, uint* __restrict__ gcur_s,
    uint* __restrict__ tmp_r, uint* __restrict__ tmp_s, int E, int NB) {
  __shared__ uint hist[NBMAX], lstart[NBMAX], cur[NBMAX], gbase[NBMAX];
  __shared__ uint ids[DC];
  __shared__ ushort idsB[DC];
  __shared__ uint ts[256];
  int dir = blockIdx.x & 1;
  const int* key = dir ? senders : receivers;
  uint* g_cursor = dir ? gcur_s : gcur_r;
  uint* tmp = dir ? tmp_s : tmp_r;
  int t = threadIdx.x;
  int base = (blockIdx.x >> 1) * DC;
  int cact = min(DC, E - base);
  for (int i = t; i < NB; i += 256) hist[i] = 0;
  __syncthreads();
  for (int k = 0; k < DC / 256; ++k) {
    int j = k * 256 + t;
    if (j < cact) atomicAdd(&hist[key[base + j] >> BSHIFT], 1u);
  }
  __syncthreads();
  {
    uint loc[4]; uint tsum = 0;
    #pragma unroll
    for (int q = 0; q < 4; ++q) {
      int i = t * 4 + q;
      loc[q] = (i < NB) ? hist[i] : 0;
      tsum += loc[q];
    }
    ts[t] = tsum;
    __syncthreads();
    for (int off = 1; off < 256; off <<= 1) {
      uint a = (t >= off) ? ts[t - off] : 0;
      __syncthreads();
      ts[t] += a;
      __syncthreads();
    }
    uint run = ts[t] - tsum;
    #pragma unroll
    for (int q = 0; q < 4; ++q) {
      int i = t * 4 + q;
      if (i < NB) { lstart[i] = run; cur[i] = run; run += loc[q]; }
    }
  }
  __syncthreads();
  for (int i = t; i < NB; i += 256)
    if (hist[i]) gbase[i] = atomicAdd(&g_cursor[i], hist[i]);
  for (int k = 0; k < DC / 256; ++k) {
    int j = k * 256 + t;
    if (j < cact) {
      int e = base + j;
      int kk = key[e];
      uint b = (uint)(kk >> BSHIFT);
      uint slot = atomicAdd(&cur[b], 1u);
      ids[slot] = ((uint)(kk & (BW - 1)) << 21) | (uint)e;
      idsB[slot] = (ushort)b;
    }
  }
  __syncthreads();
  for (int j = t; j < cact; j += 256) {
    uint b2 = idsB[j];
    tmp[gbase[b2] + ((uint)j - lstart[b2])] = ids[j];
  }
}

// ---- per-bucket counting sort to full per-node order.
__global__ __launch_bounds__(256) void bucketsort_kernel(
    const uint* __restrict__ tmp_r, const uint* __restrict__ tmp_s,
    const uint* __restrict__ start_r, const uint* __restrict__ start_s,
    uint* __restrict__ eidx_r, uint* __restrict__ eidx_s,
    uint* __restrict__ cnt_r, uint* __restrict__ cnt_s, int N) {
  __shared__ uint hist[BW], pfx[BW], cur[BW];
  int d = blockIdx.x & 1;
  int b = blockIdx.x >> 1;
  const uint* tmp = d ? tmp_s : tmp_r;
  const uint* start = d ? start_s : start_r;
  uint* eidx = d ? eidx_s : eidx_r;
  uint* cnt = d ? cnt_s : cnt_r;
  int t = threadIdx.x;
  if (t < BW) hist[t] = 0;
  __syncthreads();
  int beg = (int)start[b], end = (int)start[b + 1];
  for (int i = beg + t; i < end; i += 256) atomicAdd(&hist[tmp[i] >> 21], 1u);
  __syncthreads();
  if (t < BW) pfx[t] = hist[t];
  __syncthreads();
  for (int off = 1; off < BW; off <<= 1) {
    uint a = 0;
    if (t < BW && t >= off) a = pfx[t - off];
    __syncthreads();
    if (t < BW) pfx[t] += a;
    __syncthreads();
  }
  if (t < BW) cur[t] = pfx[t] - hist[t];
  __syncthreads();
  for (int i = beg + t; i < end; i += 256) {
    uint v = tmp[i];
    uint nl = v >> 21;
    uint p = atomicAdd(&cur[nl], 1u);
    eidx[beg + p] = v & EMASK;
  }
  int nbase = b * BW;
  if (t < BW && nbase + t < N) cnt[nbase + t] = hist[t];
}

// ---- FUSED edge-MLP + aggregation: edges in node-sorted order; segment
// sums go straight to sum_recv/sum_sent. Barrier-free (wave-local LDS).
__global__ __launch_bounds__(256, 4) void escatter_kernel(
    const float* __restrict__ edge_attr, const ushort* __restrict__ xb,
    const int* __restrict__ senders, const int* __restrict__ receivers,
    const uint* __restrict__ eidx_r, const uint* __restrict__ eidx_s,
    const ushort* __restrict__ wt_lin, const float* __restrict__ eb_init,
    float* __restrict__ sum_recv, float* __restrict__ sum_sent, int E,
    int ntiles) {
  __shared__ float Clds[4][16 * 72];  // fp32, wave-local
  __shared__ int nodeW[4][16];
  int t = threadIdx.x;
  int wid = t >> 6, l = t & 63;
  int lrow = l & 15, lk = l >> 4;
  // B-fragments (W) in registers, loaded once (r14-validated layout)
  bf16x8 b0[4], b1[4];
  float ebi[4];
  #pragma unroll
  for (int nt = 0; nt < 4; ++nt) {
    const ushort* wr = wt_lin + (nt * 16 + lrow) * 64;
    b0[nt] = *reinterpret_cast<const bf16x8*>(wr + lk * 8);
    b1[nt] = *reinterpret_cast<const bf16x8*>(wr + 32 + lk * 8);
    ebi[nt] = eb_init[nt * 16 + lrow];
  }
  const bf16x8 zero8 = {0, 0, 0, 0, 0, 0, 0, 0};
  int dir = blockIdx.x & 1;
  const uint* eidx = dir ? eidx_s : eidx_r;
  float* sum = dir ? sum_sent : sum_recv;
  int gw = (blockIdx.x >> 1) * 4 + wid;
  int nw = (gridDim.x >> 1) * 4;
  for (int tile = gw; tile < ntiles; tile += nw) {
    int m = tile * 16 + lrow;
    int mc = min(m, E - 1);
    int e = (int)eidx[mc];
    int r = receivers[e];
    int s = senders[e];
    if (lk == 0) nodeW[wid][lrow] = dir ? s : r;
    bf16x8 a0, a1;
    if (lk < 2) {
      const float* ap = edge_attr + (size_t)e * 16 + lk * 8;
      float4 f0 = LDF4(ap), f1 = LDF4(ap + 4);
      union { ushort h[8]; bf16x8 v; } pk;
      pk.h[0] = f2bf(f0.x); pk.h[1] = f2bf(f0.y);
      pk.h[2] = f2bf(f0.z); pk.h[3] = f2bf(f0.w);
      pk.h[4] = f2bf(f1.x); pk.h[5] = f2bf(f1.y);
      pk.h[6] = f2bf(f1.z); pk.h[7] = f2bf(f1.w);
      a0 = pk.v;
      a1 = *reinterpret_cast<const bf16x8*>(xb + (size_t)s * 16 + lk * 8);
    } else {
      a0 = *reinterpret_cast<const bf16x8*>(xb + (size_t)r * 16 +
                                            (lk - 2) * 8);
      a1 = zero8;
    }
    f32x4 acc[4];
    #pragma unroll
    for (int nt = 0; nt < 4; ++nt) {
      acc[nt] = f32x4{ebi[nt], ebi[nt], ebi[nt], ebi[nt]};
      acc[nt] =
          __builtin_amdgcn_mfma_f32_16x16x32_bf16(a0, b0[nt], acc[nt], 0, 0, 0);
      acc[nt] =
          __builtin_amdgcn_mfma_f32_16x16x32_bf16(a1, b1[nt], acc[nt], 0, 0, 0);
    }
    // relu -> wave-local fp32 tile (row = edge-in-tile, col = feature)
    int m0 = (l >> 4) * 4;
    #pragma unroll
    for (int nt = 0; nt < 4; ++nt) {
      #pragma unroll
      for (int reg = 0; reg < 4; ++reg) {
        Clds[wid][(m0 + reg) * 72 + nt * 16 + lrow] =
            fmaxf(acc[nt][reg], 0.f);
      }
    }
    // wave-uniform segmented sum over the tile's node runs
    int vc = min(16, E - tile * 16);
    float accum = 0.f;
    int prev = nodeW[wid][0];
    for (int mm = 0; mm < vc; ++mm) {
      int nd = nodeW[wid][mm];
      float v = Clds[wid][mm * 72 + l];
      if (nd != prev) {
        atomicAdd(&sum[(size_t)prev * 64 + l], accum);
        accum = 0.f;
        prev = nd;
      }
      accum += v;
    }
    atomicAdd(&sum[(size_t)prev * 64 + l], accum);
  }
}

// ---- node block via MFMA: n_h(bf16) = relu([sum_recv, x]@W_nb + nb_init)
__global__ __launch_bounds__(256, 2) void node_mfma_kernel(
    const float* __restrict__ sum_recv, const ushort* __restrict__ xb,
    const ushort* __restrict__ wnb_img, const float* __restrict__ nb_init,
    ushort* __restrict__ n_h, int N) {
  __shared__ ushort Alds[64 * 128];      // 16 KB
  __shared__ ushort Wlds[64 * 128];      // 16 KB
  __shared__ ushort Clds[4][16 * 72];    // 9 KB
  int t = threadIdx.x;
  int base = blockIdx.x * 64;
  {
    const uint4* src = reinterpret_cast<const uint4*>(wnb_img);
    uint4* dst = reinterpret_cast<uint4*>(Wlds);
    #pragma unroll
    for (int i = 0; i < 4; ++i) dst[t + 256 * i] = src[t + 256 * i];
  }
  {
    int m = t >> 2, part = t & 3;
    int n = base + m;
    bool val = n < N;
    if (part < 2) {
      #pragma unroll
      for (int q = 0; q < 4; ++q) {
        int c = part * 4 + q;
        union { ushort h[8]; uint4 qq; } pk;
        if (val) {
          const float* src = sum_recv + (size_t)n * 64 + c * 8;
          float4 f0 = LDF4(src), f1 = LDF4(src + 4);
          pk.h[0] = f2bf(f0.x); pk.h[1] = f2bf(f0.y);
          pk.h[2] = f2bf(f0.z); pk.h[3] = f2bf(f0.w);
          pk.h[4] = f2bf(f1.x); pk.h[5] = f2bf(f1.y);
          pk.h[6] = f2bf(f1.z); pk.h[7] = f2bf(f1.w);
        } else {
          pk.qq = uint4{0, 0, 0, 0};
        }
        *reinterpret_cast<uint4*>(&Alds[nswz(m, c)]) = pk.qq;
      }
    } else if (part == 2) {
      uint4 w0 = {0, 0, 0, 0}, w1 = {0, 0, 0, 0};
      if (val) {
        const uint4* xp = reinterpret_cast<const uint4*>(xb + (size_t)n * 16);
        w0 = xp[0]; w1 = xp[1];
      }
      *reinterpret_cast<uint4*>(&Alds[nswz(m, 8)]) = w0;
      *reinterpret_cast<uint4*>(&Alds[nswz(m, 9)]) = w1;
      *reinterpret_cast<uint4*>(&Alds[nswz(m, 10)]) = uint4{0, 0, 0, 0};
      *reinterpret_cast<uint4*>(&Alds[nswz(m, 11)]) = uint4{0, 0, 0, 0};
    } else {
      #pragma unroll
      for (int q = 0; q < 4; ++q)
        *reinterpret_cast<uint4*>(&Alds[nswz(m, 12 + q)]) = uint4{0, 0, 0, 0};
    }
  }
  __syncthreads();
  int wid = t >> 6, l = t & 63;
  int lrow = l & 15, lk = l >> 4;
  int arow = wid * 16 + lrow;
  bf16x8 afr[4];
  #pragma unroll
  for (int g = 0; g < 4; ++g)
    afr[g] = *reinterpret_cast<const bf16x8*>(&Alds[nswz(arow, g * 4 + lk)]);
  f32x4 acc[4];
  #pragma unroll
  for (int nt = 0; nt < 4; ++nt) {
    float nbi = nb_init[nt * 16 + lrow];
    acc[nt] = f32x4{nbi, nbi, nbi, nbi};
    #pragma unroll
    for (int g = 0; g < 4; ++g) {
      bf16x8 b = *reinterpret_cast<const bf16x8*>(
          &Wlds[nswz(nt * 16 + lrow, g * 4 + lk)]);
      acc[nt] =
          __builtin_amdgcn_mfma_f32_16x16x32_bf16(afr[g], b, acc[nt], 0, 0, 0);
    }
  }
  int m0 = (l >> 4) * 4;
  #pragma unroll
  for (int nt = 0; nt < 4; ++nt) {
    #pragma unroll
    for (int reg = 0; reg < 4; ++reg) {
      Clds[wid][(m0 + reg) * 72 + nt * 16 + lrow] =
          f2bf(fmaxf(acc[nt][reg], 0.f));
    }
  }
  __syncthreads();
  int sm = l >> 2, ch = l & 3;
  int gn = base + wid * 16 + sm;
  uint4 c0 = *reinterpret_cast<const uint4*>(&Clds[wid][sm * 72 + ch * 16]);
  uint4 c1 = *reinterpret_cast<const uint4*>(&Clds[wid][sm * 72 + ch * 16 + 8]);
  if (gn < N) {
    uint4* dst = reinterpret_cast<uint4*>(n_h + (size_t)gn * 64 + ch * 16);
    dst[0] = c0;
    dst[1] = c1;
  }
}

// ---- column sums of sum_recv (fp32) and n_h (bf16)
__global__ __launch_bounds__(256) void reduce_kernel(
    const float* __restrict__ sum_recv, const ushort* __restrict__ n_h,
    float* __restrict__ e_sum, float* __restrict__ n_sum, int N) {
  __shared__ float ls[128];
  if (threadIdx.x < 128) ls[threadIdx.x] = 0.f;
  __syncthreads();
  int g = threadIdx.x & 15;
  int tid = blockIdx.x * blockDim.x + threadIdx.x;
  int row0 = tid >> 4;
  int rstride = (gridDim.x * blockDim.x) >> 4;
  float pe[4] = {0, 0, 0, 0}, pn[4] = {0, 0, 0, 0};
  for (int r = row0; r < N; r += rstride) {
    float4 a = LDF4(sum_recv + (size_t)r * 64 + g * 4);
    uint2 b = *reinterpret_cast<const uint2*>(n_h + (size_t)r * 64 + g * 4);
    pe[0] += a.x; pe[1] += a.y; pe[2] += a.z; pe[3] += a.w;
    pn[0] += __uint_as_float(b.x << 16);
    pn[1] += __uint_as_float(b.x & 0xFFFF0000u);
    pn[2] += __uint_as_float(b.y << 16);
    pn[3] += __uint_as_float(b.y & 0xFFFF0000u);
  }
  #pragma unroll
  for (int i = 0; i < 4; ++i) {
    atomicAdd(&ls[g * 4 + i], pe[i]);
    atomicAdd(&ls[64 + g * 4 + i], pn[i]);
  }
  __syncthreads();
  if (threadIdx.x < 64) {
    atomicAdd(&e_sum[threadIdx.x], ls[threadIdx.x]);
    atomicAdd(&n_sum[threadIdx.x], ls[64 + threadIdx.x]);
  }
}

// ---- global block + fold u2 into d1_init
__global__ void global_kernel(const float* __restrict__ u,
                              const float* __restrict__ e_sum,
                              const float* __restrict__ n_sum,
                              const float* __restrict__ W_gb,
                              const float* __restrict__ b_gb,
                              const float* __restrict__ W_d1,
                              const float* __restrict__ b_d1,
                              float* __restrict__ d1_init, float Ef, float Nf) {
  __shared__ float gin[192];
  __shared__ float u2s[64];
  int j = threadIdx.x;  // 64 threads
  gin[j] = e_sum[j] / Ef;
  gin[64 + j] = n_sum[j] / Nf;
  gin[128 + j] = u[j];
  __syncthreads();
  float a = b_gb[j];
  for (int k = 0; k < 192; ++k) a = fmaf(gin[k], W_gb[k * 64 + j], a);
  u2s[j] = fmaxf(a, 0.f);
  __syncthreads();
  float d = b_d1[j];
  for (int k = 0; k < 64; ++k) d = fmaf(u2s[k], W_d1[(192 + k) * 64 + j], d);
  d1_init[j] = d;
}

// ---- decoder via MFMA: out = relu(A@W_d1 + d1_init) @ W_d2 + b_d2
__global__ __launch_bounds__(256, 2) void decoder_mfma_kernel(
    const float* __restrict__ sum_recv, const float* __restrict__ sum_sent,
    const uint* __restrict__ cnt_r, const uint* __restrict__ cnt_s,
    const ushort* __restrict__ n_h, const ushort* __restrict__ wtd1_img,
    const float* __restrict__ d1_init, const ushort* __restrict__ w2_img,
    const float* __restrict__ b_d2, float* __restrict__ out, int N) {
  __shared__ ushort Alds[64 * 192];   // 24 KB
  __shared__ ushort Wlds[64 * 192];   // 24 KB
  __shared__ ushort Hlds[64 * 64];    // 8 KB
  __shared__ ushort W2lds[16 * 64];   // 2 KB
  int t = threadIdx.x;
  int base = blockIdx.x * 64;
  {
    const uint4* src = reinterpret_cast<const uint4*>(wtd1_img);
    uint4* dst = reinterpret_cast<uint4*>(Wlds);
    #pragma unroll
    for (int i = 0; i < 6; ++i) dst[t + 256 * i] = src[t + 256 * i];
    if (t < 128)
      reinterpret_cast<uint4*>(W2lds)[t] =
          reinterpret_cast<const uint4*>(w2_img)[t];
  }
  {
    int m = t >> 2;
    int n = base + m;
    bool val = n < N;
    float invr = 0.f, invs = 0.f;
    if (val) {
      invr = 1.f / fmaxf((float)cnt_r[n], 1.f);
      invs = 1.f / fmaxf((float)cnt_s[n], 1.f);
    }
    int c0 = (t & 3) * 6;
    for (int c = c0; c < c0 + 6; ++c) {
      union { ushort h[8]; uint4 q; } pk;
      if (val) {
        if (c >= 16) {
          pk.q = *reinterpret_cast<const uint4*>(n_h + (size_t)n * 64 +
                                                 (c - 16) * 8);
        } else {
          const float* src;
          float scl;
          if (c < 8) { src = sum_recv + (size_t)n * 64 + c * 8; scl = invr; }
          else       { src = sum_sent + (size_t)n * 64 + (c - 8) * 8; scl = invs; }
          float4 f0 = LDF4(src), f1 = LDF4(src + 4);
          pk.h[0] = f2bf(f0.x * scl); pk.h[1] = f2bf(f0.y * scl);
          pk.h[2] = f2bf(f0.z * scl); pk.h[3] = f2bf(f0.w * scl);
          pk.h[4] = f2bf(f1.x * scl); pk.h[5] = f2bf(f1.y * scl);
          pk.h[6] = f2bf(f1.z * scl); pk.h[7] = f2bf(f1.w * scl);
        }
      } else {
        pk.q = uint4{0, 0, 0, 0};
      }
      *reinterpret_cast<uint4*>(&Alds[aswz192(m, c)]) = pk.q;
    }
  }
  __syncthreads();
  int wid = t >> 6, l = t & 63;
  int lrow = l & 15, lk = l >> 4;
  int arow = wid * 16 + lrow;
  bf16x8 afr[6];
  #pragma unroll
  for (int g = 0; g < 6; ++g)
    afr[g] = *reinterpret_cast<const bf16x8*>(&Alds[aswz192(arow, g * 4 + lk)]);
  f32x4 acc[4];
  #pragma unroll
  for (int nt = 0; nt < 4; ++nt) {
    float di = d1_init[nt * 16 + lrow];
    acc[nt] = f32x4{di, di, di, di};
    #pragma unroll
    for (int g = 0; g < 6; ++g) {
      bf16x8 b = *reinterpret_cast<const bf16x8*>(
          &Wlds[aswz192(nt * 16 + lrow, g * 4 + lk)]);
      acc[nt] =
          __builtin_amdgcn_mfma_f32_16x16x32_bf16(afr[g], b, acc[nt], 0, 0, 0);
    }
  }
  int m0 = (l >> 4) * 4;
  #pragma unroll
  for (int nt = 0; nt < 4; ++nt) {
    #pragma unroll
    for (int reg = 0; reg < 4; ++reg) {
      int hm = wid * 16 + m0 + reg;
      int hn = nt * 16 + lrow;
      Hlds[hm * 64 + (((hn >> 3) ^ (hm & 7)) << 3) + (hn & 7)] =
          f2bf(fmaxf(acc[nt][reg], 0.f));
    }
  }
  __syncthreads();
  bf16x8 a20 = *reinterpret_cast<const bf16x8*>(&Hlds[aswz(arow, lk)]);
  bf16x8 a21 = *reinterpret_cast<const bf16x8*>(&Hlds[aswz(arow, 4 + lk)]);
  bf16x8 b20 = *reinterpret_cast<const bf16x8*>(&W2lds[aswz(lrow, lk)]);
  bf16x8 b21 = *reinterpret_cast<const bf16x8*>(&W2lds[aswz(lrow, 4 + lk)]);
  float bi = b_d2[lrow];
  f32x4 o = f32x4{bi, bi, bi, bi};
  o = __builtin_amdgcn_mfma_f32_16x16x32_bf16(a20, b20, o, 0, 0, 0);
  o = __builtin_amdgcn_mfma_f32_16x16x32_bf16(a21, b21, o, 0, 0, 0);
  #pragma unroll
  for (int reg = 0; reg < 4; ++reg) {
    int ge = base + wid * 16 + m0 + reg;
    if (ge < N) out[(size_t)ge * 16 + lrow] = o[reg];
  }
}

extern "C" void kernel_launch(void* const* d_in, const int* in_sizes, int n_in,
                              void* d_out, int out_size, void* d_ws,
                              size_t ws_size, hipStream_t stream) {
  const float* x         = (const float*)d_in[0];
  const float* edge_attr = (const float*)d_in[1];
  const float* u         = (const float*)d_in[2];
  const int*   senders   = (const int*)d_in[3];
  const int*   receivers = (const int*)d_in[4];
  const float* W_eb = (const float*)d_in[7];
  const float* b_eb = (const float*)d_in[8];
  const float* W_nb = (const float*)d_in[9];
  const float* b_nb = (const float*)d_in[10];
  const float* W_gb = (const float*)d_in[11];
  const float* b_gb = (const float*)d_in[12];
  const float* W_d1 = (const float*)d_in[13];
  const float* b_d1 = (const float*)d_in[14];
  const float* W_d2 = (const float*)d_in[15];
  const float* b_d2 = (const float*)d_in[16];

  int N = in_sizes[0] / 16;
  int E = in_sizes[1] / 16;
  int NB = (N + BW - 1) >> BSHIFT;  // 782 for N=100000
  int NDB = (E + DC - 1) / DC;      // distribute chunks per direction
  int ntiles = (E + 15) / 16;

  char* w = (char*)d_ws;
  float* sum_recv = (float*)w;       w += (size_t)N * 64 * 4;
  float* sum_sent = (float*)w;       w += (size_t)N * 64 * 4;
  ushort* n_h = (ushort*)w;          w += (size_t)N * 64 * 2;
  uint* tmp_r = (uint*)w;            w += (size_t)E * 4;
  uint* tmp_s = (uint*)w;            w += (size_t)E * 4;
  uint* eidx_r = (uint*)w;           w += (size_t)E * 4;
  uint* eidx_s = (uint*)w;           w += (size_t)E * 4;
  uint* cnt_r = (uint*)w;            w += (size_t)N * 4;
  uint* cnt_s = (uint*)w;            w += (size_t)N * 4;
  ushort* xb = (ushort*)w;           w += (size_t)N * 16 * 2;
  ushort* wt_lin = (ushort*)w;       w += (size_t)64 * 64 * 2;
  ushort* wnb_img = (ushort*)w;      w += (size_t)64 * 128 * 2;
  ushort* wtd1_img = (ushort*)w;     w += (size_t)64 * 192 * 2;
  ushort* w2_img = (ushort*)w;       w += (size_t)16 * 64 * 2;
  uint* start_r = (uint*)w;          w += (size_t)(NB + 1) * 4;
  uint* start_s = (uint*)w;          w += (size_t)(NB + 1) * 4;
  uint* cur_r = (uint*)w;            w += (size_t)NB * 4;
  uint* cur_s = (uint*)w;            w += (size_t)NB * 4;
  // zeroed region
  uint* bcnt_r = (uint*)w;           w += (size_t)NBMAX * 4;
  uint* bcnt_s = (uint*)w;           w += (size_t)NBMAX * 4;
  float* e_sum = (float*)w;          w += 64 * 4;
  float* n_sum = (float*)w;          w += 64 * 4;
  // small non-zeroed
  float* eb_init = (float*)w;        w += 64 * 4;
  float* nb_init = (float*)w;        w += 64 * 4;
  float* d1_init = (float*)w;        w += 64 * 4;

  size_t zero_bytes = (size_t)(2 * NBMAX + 128) * 4;
  hipMemsetAsync(bcnt_r, 0, zero_bytes, stream);
  // zero the atomic accumulation targets (sum_recv | sum_sent contiguous)
  hipMemsetAsync(sum_recv, 0, (size_t)N * 128 * 4, stream);

  hipLaunchKernelGGL(init_kernel, dim3(1 + (N * 16 / 4 + 255) / 256), dim3(256),
                     0, stream, x, xb, N * 16, u, W_eb, b_eb, W_nb, b_nb, W_d1,
                     W_d2, eb_init, nb_init, wt_lin, wnb_img, wtd1_img, w2_img);
  hipLaunchKernelGGL(bcount_kernel, dim3(64), dim3(256), 0, stream, receivers,
                     senders, bcnt_r, bcnt_s, E, NB);
  hipLaunchKernelGGL(bscan_kernel, dim3(1), dim3(256), 0, stream, bcnt_r,
                     bcnt_s, start_r, start_s, cur_r, cur_s, E, NB);
  hipLaunchKernelGGL(distribute_kernel, dim3(2 * NDB), dim3(256), 0, stream,
                     receivers, senders, cur_r, cur_s, tmp_r, tmp_s, E, NB);
  hipLaunchKernelGGL(bucketsort_kernel, dim3(2 * NB), dim3(256), 0, stream,
                     tmp_r, tmp_s, start_r, start_s, eidx_r, eidx_s, cnt_r,
                     cnt_s, N);
  hipLaunchKernelGGL(escatter_kernel, dim3(2048), dim3(256), 0, stream,
                     edge_attr, xb, senders, receivers, eidx_r, eidx_s, wt_lin,
                     eb_init, sum_recv, sum_sent, E, ntiles);
  hipLaunchKernelGGL(node_mfma_kernel, dim3((N + 63) / 64), dim3(256), 0,
                     stream, sum_recv, xb, wnb_img, nb_init, n_h, N);
  hipLaunchKernelGGL(reduce_kernel, dim3(256), dim3(256), 0, stream, sum_recv,
                     n_h, e_sum, n_sum, N);
  hipLaunchKernelGGL(global_kernel, dim3(1), dim3(64), 0, stream, u, e_sum,
                     n_sum, W_gb, b_gb, W_d1, b_d1, d1_init, (float)E,
                     (float)N);
  hipLaunchKernelGGL(decoder_mfma_kernel, dim3((N + 63) / 64), dim3(256), 0,
                     stream, sum_recv, sum_sent, cnt_r, cnt_s, n_h, wtd1_img,
                     d1_init, w2_img, b_d2, (float*)d_out, N);
}